// Round 7
// baseline (3301.822 us; speedup 1.0000x reference)
//
#include <hip/hip_runtime.h>
#include <stdint.h>

typedef unsigned short u16;
typedef unsigned int   u32;
typedef __bf16 bf16x8 __attribute__((ext_vector_type(8)));
typedef float  f32x4  __attribute__((ext_vector_type(4)));
typedef u16    u16x8  __attribute__((ext_vector_type(8)));
typedef u32    u32x2  __attribute__((ext_vector_type(2)));
typedef u32    u32x4  __attribute__((ext_vector_type(4)));

#define TBROWS 32704   // 511 * 64 valid (t,b) rows

__device__ __forceinline__ u16 f2bf(float f) {
  union { float f; u32 u; } v; v.f = f;
  u32 r = v.u + 0x7FFFu + ((v.u >> 16) & 1u);   // RNE
  return (u16)(r >> 16);
}
__device__ __forceinline__ float bf2f(u16 h) {
  union { u32 u; float f; } v; v.u = ((u32)h) << 16;
  return v.f;
}
__device__ __forceinline__ float fsigmoid(float x) {
  return 1.0f / (1.0f + exp2f(-1.44269504f * x));
}
__device__ __forceinline__ float ftanh(float x) {
  return 2.0f / (1.0f + exp2f(-2.88539008f * x)) - 1.0f;
}
__device__ __forceinline__ u32 pkmaxu16(u32 a, u32 b) {
  u32 d;
  asm("v_pk_max_u16 %0, %1, %2" : "=v"(d) : "v"(a), "v"(b));
  return d;
}
// valid h (|h|<1 -> u16 code <= 0xBF80); sentinel 0xFFFF. fresh <=> all halves < 0xC000
__device__ __forceinline__ int vec_fresh(u32x4 v) {
  u32 m = pkmaxu16(pkmaxu16(v[0], v[1]), pkmaxu16(v[2], v[3]));
  return (m < 0xC0000000u) && ((m << 16) < 0xC0000000u);
}

// ---------------- conversions ----------------

// x f32 [64][512][1024] -> bf16 same layout
__global__ __launch_bounds__(256) void conv_x(const float* __restrict__ x,
                                              u16* __restrict__ xb) {
  const int n4 = (64 * 512 * 1024) / 4;
  const float4* xv = (const float4*)x;
  for (int i = blockIdx.x * 256 + threadIdx.x; i < n4; i += 4096 * 256) {
    float4 v = xv[i];
    uint2 o;
    o.x = (u32)f2bf(v.x) | ((u32)f2bf(v.y) << 16);
    o.y = (u32)f2bf(v.z) | ((u32)f2bf(v.w) << 16);
    *(uint2*)(xb + (size_t)i * 4) = o;
  }
}

// Build WbT bf16 [4096][1024]: WbT[n][k] = W_g[k][hc], n = hc*4 + g (gate-interleaved)
__global__ __launch_bounds__(256) void conv_u(const float* __restrict__ U0,
                                              const float* __restrict__ U1,
                                              const float* __restrict__ U2,
                                              const float* __restrict__ U3,
                                              u16* __restrict__ WbT) {
  __shared__ float tile[64][65];
  const int bid = blockIdx.x;
  const int g = bid >> 8, kt = (bid >> 4) & 15, ht = bid & 15;
  const float* U = (g == 0) ? U0 : (g == 1) ? U1 : (g == 2) ? U2 : U3;
  const int t = threadIdx.x;
  const int c = t & 63, r0 = t >> 6;
#pragma unroll
  for (int rr = 0; rr < 64; rr += 4)
    tile[rr + r0][c] = U[(size_t)(kt * 64 + rr + r0) * 1024 + ht * 64 + c];
  __syncthreads();
  const int hcl = t >> 2, ks = t & 3;
  const int n = (ht * 64 + hcl) * 4 + g;
  u16x8 o0, o1;
#pragma unroll
  for (int ii = 0; ii < 8; ++ii) o0[ii] = f2bf(tile[ks * 16 + ii][hcl]);
#pragma unroll
  for (int ii = 0; ii < 8; ++ii) o1[ii] = f2bf(tile[ks * 16 + 8 + ii][hcl]);
  size_t base = (size_t)n * 1024 + kt * 64 + ks * 16;
  *(u16x8*)(WbT + base) = o0;
  *(u16x8*)(WbT + base + 8) = o1;
}

// bb f32 [4096] gate-interleaved: bb[hc*4+g] = b_g[hc]
__global__ __launch_bounds__(256) void conv_b(const float* __restrict__ b0,
                                              const float* __restrict__ b1,
                                              const float* __restrict__ b2,
                                              const float* __restrict__ b3,
                                              float* __restrict__ bb) {
  int n = blockIdx.x * 256 + threadIdx.x;
  if (n < 4096) {
    int g = n & 3, hc = n >> 2;
    const float* B = (g == 0) ? b0 : (g == 1) ? b1 : (g == 2) ? b2 : b3;
    bb[n] = B[hc];
  }
}

// sentinel-fill hseq (8 bq regions x 511 slots x 16KB) + zero flags.
// Runs every call (replay-safe); kernel-end L2 flush publishes to LLC.
__global__ __launch_bounds__(256) void init_sent(u32* __restrict__ p,
                                                 int* __restrict__ flags) {
  if (blockIdx.x == 0 && threadIdx.x < 256) flags[threadIdx.x] = 0;
  const size_t n4 = 4186112;   // uint4 count = 8*511*8192*2B / 16
  uint4 s = make_uint4(0xFFFFFFFFu, 0xFFFFFFFFu, 0xFFFFFFFFu, 0xFFFFFFFFu);
  for (size_t i = blockIdx.x * 256 + threadIdx.x; i < n4; i += (size_t)2048 * 256)
    *(uint4*)(p + i * 4) = s;
}

// ---------------- phase 1: x_proj GEMM ----------------
// xp[hc][tb][g] = sum_k UbT[hc*4+g][k] * xb[tb][k] + bb  (bf16 out)
__global__ __launch_bounds__(256, 2) void gemm_xproj(const u16* __restrict__ xb,
                                                     const u16* __restrict__ UbT,
                                                     const float* __restrict__ bb,
                                                     u16* __restrict__ xp) {
  __shared__ __align__(16) u16 As[128 * 32];
  __shared__ __align__(16) u16 Bs[128 * 32];
  const int tid = threadIdx.x;
  const int lane = tid & 63, w = tid >> 6;
  const int q = lane >> 4, r15 = lane & 15;
  const int nt = blockIdx.x & 31;        // M (n) tile
  const int tt = blockIdx.x >> 5;        // N (tb) tile
  const int n_base = nt * 128;
  const long long tb_base = (long long)tt * 128;
  const int mh = w & 1, nh = w >> 1;

  f32x4 acc[4][4];
#pragma unroll
  for (int a = 0; a < 4; ++a)
#pragma unroll
    for (int b2 = 0; b2 < 4; ++b2) acc[a][b2] = (f32x4){0.f, 0.f, 0.f, 0.f};

#pragma unroll 1
  for (int kb = 0; kb < 32; ++kb) {
    __syncthreads();
    const int k0 = kb * 32;
#pragma unroll
    for (int call = 0; call < 2; ++call) {
      const int chunk = call * 256 + w * 64 + lane;
      const int row = chunk >> 2, q4 = chunk & 3;
      const u16* ga = UbT + (size_t)(n_base + row) * 1024 + k0 + q4 * 8;
      __builtin_amdgcn_global_load_lds(
          (const __attribute__((address_space(1))) void*)ga,
          (__attribute__((address_space(3))) void*)(As + (call * 256 + w * 64) * 8),
          16, 0, 0);
      long long tbr = tb_base + row;
      if (tbr > TBROWS - 1) tbr = TBROWS - 1;
      const int xbrow = ((int)tbr & 63) * 512 + ((int)tbr >> 6);  // (b,t) -> x row
      const u16* gb = xb + (size_t)xbrow * 1024 + k0 + q4 * 8;
      __builtin_amdgcn_global_load_lds(
          (const __attribute__((address_space(1))) void*)gb,
          (__attribute__((address_space(3))) void*)(Bs + (call * 256 + w * 64) * 8),
          16, 0, 0);
    }
    __syncthreads();
    bf16x8 af[4], bfr[4];
#pragma unroll
    for (int m = 0; m < 4; ++m)
      af[m] = *(const bf16x8*)(As + ((mh * 64 + m * 16 + r15) * 32 + q * 8));
#pragma unroll
    for (int n2 = 0; n2 < 4; ++n2)
      bfr[n2] = *(const bf16x8*)(Bs + ((nh * 64 + n2 * 16 + r15) * 32 + q * 8));
#pragma unroll
    for (int m = 0; m < 4; ++m)
#pragma unroll
      for (int n2 = 0; n2 < 4; ++n2)
        acc[m][n2] = __builtin_amdgcn_mfma_f32_16x16x32_bf16(af[m], bfr[n2],
                                                             acc[m][n2], 0, 0, 0);
  }
#pragma unroll
  for (int m = 0; m < 4; ++m) {
    const int nrow = n_base + mh * 64 + m * 16 + q * 4;
    const float4 bias = *(const float4*)(bb + nrow);
    const long long hcb = (long long)(nrow >> 2) * TBROWS;
#pragma unroll
    for (int n2 = 0; n2 < 4; ++n2) {
      const long long tb = tb_base + nh * 64 + n2 * 16 + r15;
      if (tb < TBROWS) {
        const f32x4 v = acc[m][n2];
        uint2 pk;
        pk.x = (u32)f2bf(v[0] + bias.x) | ((u32)f2bf(v[1] + bias.y) << 16);
        pk.y = (u32)f2bf(v[2] + bias.z) | ((u32)f2bf(v[3] + bias.w) << 16);
        *(uint2*)(xp + (hcb + tb) * 4) = pk;
      }
    }
  }
}

// ---------------- phase 2: persistent recurrence ----------------
// NEW geometry: 256 blocks = 32 hc-groups (32 hc each) x 8 batch-octets (8 b).
// Per-step LLC reads: 16KB/block (4 MB/step total, 2x less than R6).
// 4 waves/block K-split (256 k each); V fragments register-resident (256 VGPR).
// Protocol = R6-proven: sc0 sc1 everywhere, write-once sentinel slots,
// in-band validation is the sole correctness gate, flags advisory, bounded
// spins. First pass issues data speculatively (saves one RT on fast path).
__global__ __launch_bounds__(256, 1) void lstm_rec(
    const u16* __restrict__ VbT, const u16* __restrict__ xp,
    u16* hseq, int* flags, float* __restrict__ out) {
  __shared__ __align__(16) f32x4 part[2][4][8][64];   // [parity][wave][tile][lane] 64KB
  const int tid = threadIdx.x;
  const int lane = tid & 63;
  const int w = tid >> 6;          // wave = K-quarter [w*256,(w+1)*256)
  const int q = lane >> 4;
  const int r15 = lane & 15;
  const int be = r15 & 7;          // batch within octet (cols 0-7 / 8-15 duplicate)
  const int j = blockIdx.x & 31;   // hc group (32 hidden units)
  const int bq = blockIdx.x >> 5;  // batch octet (8 batches)
  const int b = bq * 8 + be;

  // ---- A fragments (reg-resident, 256 VGPR): areg[t][kkl]
  // A[zrow = j*128 + t*16 + r15][k = w*256 + kkl*32 + q*8 + jj]
  bf16x8 areg[8][8];
#pragma unroll
  for (int t = 0; t < 8; ++t)
#pragma unroll
    for (int kkl = 0; kkl < 8; ++kkl)
      areg[t][kkl] = *(const bf16x8*)(
          VbT + (size_t)(j * 128 + t * 16 + r15) * 1024 + w * 256 + kkl * 32 + q * 8);

  // lane output identity: tiles 2w,2w+1 -> hc0/hc1; 4 gates in acc regs
  const int hc0 = j * 32 + 8 * w + q;
  const int hc1 = hc0 + 4;
  const u16* xpp0 = xp + (size_t)hc0 * TBROWS * 4 + (size_t)b * 4;
  const u16* xpp1 = xp + (size_t)hc1 * TBROWS * 4 + (size_t)b * 4;
  u16* bqslot = hseq + (size_t)bq * (511 * 8192);
  const int loff = be * 1024 + w * 256 + q * 8;       // consumer load offset
  const int* fpp = flags + bq * 32 + w * 8 + be;      // advisory flags (8/wave)
  float c0 = 0.f, c1 = 0.f;

  u32x2 xv0, xv1, xn0, xn1;
  asm volatile("global_load_dwordx2 %0, %1, off" : "=v"(xv0) : "v"(xpp0) : "memory");
  asm volatile("global_load_dwordx2 %0, %1, off" : "=v"(xv1) : "v"(xpp1) : "memory");
  asm volatile("s_waitcnt vmcnt(0)" ::: "memory");
  __builtin_amdgcn_sched_barrier(0);

#pragma unroll 1
  for (int it = 0; it < 512; ++it) {
    u32x4 hb[8];
    if (it > 0) {
      const u16* hpl = bqslot + (size_t)(it - 1) * 8192 + loff;
      int fr0 = 0, fr1 = 0, fr2 = 0, fr3 = 0, fr4 = 0, fr5 = 0, fr6 = 0, fr7 = 0;
      int passes = 256;
#pragma unroll 1
      for (;;) {
#define LOADV(i) if (!fr##i) \
        asm volatile("global_load_dwordx4 %0, %1, off sc0 sc1" \
                     : "=v"(hb[i]) : "v"(hpl + i * 32) : "memory");
        LOADV(0) LOADV(1) LOADV(2) LOADV(3) LOADV(4) LOADV(5) LOADV(6) LOADV(7)
#undef LOADV
        asm volatile("s_waitcnt vmcnt(0)" ::: "memory");
        __builtin_amdgcn_sched_barrier(0);
#define CHECKV(i) if (!fr##i) fr##i = __all(vec_fresh(hb[i]));
        CHECKV(0) CHECKV(1) CHECKV(2) CHECKV(3) CHECKV(4) CHECKV(5) CHECKV(6) CHECKV(7)
#undef CHECKV
        if (fr0 && fr1 && fr2 && fr3 && fr4 && fr5 && fr6 && fr7) break;
        if (--passes < 0) break;   // fail fast, never hang
        // advisory: idle on 4B flag polls (avoid 128B re-read storm)
        int fb = 1 << 13;
#pragma unroll 1
        while (fb-- > 0) {
          int fv = __hip_atomic_load(fpp, __ATOMIC_RELAXED, __HIP_MEMORY_SCOPE_AGENT);
          if (__all(fv >= it)) break;
        }
      }
      // xp prefetch from last iter is drained by the poll's vmcnt(0) (rule 18)
      __builtin_amdgcn_sched_barrier(0);
      xv0 = xn0; xv1 = xn1;
    }

    // issue next xp row (drained by next iteration's validate-loop vmcnt(0))
    if (it < 511) {
      const size_t adv = (size_t)(it + 1 < 511 ? it + 1 : 510) * 256;
      asm volatile("global_load_dwordx2 %0, %1, off" : "=v"(xn0) : "v"(xpp0 + adv) : "memory");
      asm volatile("global_load_dwordx2 %0, %1, off" : "=v"(xn1) : "v"(xpp1 + adv) : "memory");
    }

    f32x4 acc[8];
#pragma unroll
    for (int t = 0; t < 8; ++t) acc[t] = (f32x4){0.f, 0.f, 0.f, 0.f};
    if (it > 0) {
#pragma unroll
      for (int kkl = 0; kkl < 8; ++kkl) {
        union { u32x4 u; bf16x8 v; } bu; bu.u = hb[kkl];
#pragma unroll
        for (int t = 0; t < 8; ++t)
          acc[t] = __builtin_amdgcn_mfma_f32_16x16x32_bf16(areg[t][kkl], bu.v,
                                                           acc[t], 0, 0, 0);
      }
    }

    // cross-wave K-reduction via LDS (parity double-buffered, one barrier)
    const int par = it & 1;
#pragma unroll
    for (int t = 0; t < 8; ++t) part[par][w][t][lane] = acc[t];
    __syncthreads();
    f32x4 z0 = part[par][0][2 * w][lane];
    f32x4 z1 = part[par][0][2 * w + 1][lane];
#pragma unroll
    for (int pw = 1; pw < 4; ++pw) {
      z0 += part[par][pw][2 * w][lane];
      z1 += part[par][pw][2 * w + 1][lane];
    }

    const float zi0 = z0[0] + bf2f((u16)(xv0[0] & 0xffff));
    const float zf0 = z0[1] + bf2f((u16)(xv0[0] >> 16));
    const float zg0 = z0[2] + bf2f((u16)(xv0[1] & 0xffff));
    const float zo0 = z0[3] + bf2f((u16)(xv0[1] >> 16));
    const float zi1 = z1[0] + bf2f((u16)(xv1[0] & 0xffff));
    const float zf1 = z1[1] + bf2f((u16)(xv1[0] >> 16));
    const float zg1 = z1[2] + bf2f((u16)(xv1[1] & 0xffff));
    const float zo1 = z1[3] + bf2f((u16)(xv1[1] >> 16));
    c0 = fsigmoid(zf0) * c0 + fsigmoid(zi0) * ftanh(zg0);
    c1 = fsigmoid(zf1) * c1 + fsigmoid(zi1) * ftanh(zg1);
    const float h0 = fsigmoid(zo0) * ftanh(c0);
    const float h1 = fsigmoid(zo1) * ftanh(c1);

    if (it == 511) {
      if (r15 < 8) {
        out[(size_t)b * 1024 + hc0] = h0;
        out[(size_t)b * 1024 + hc1] = h1;
      }
    } else {
      u32 hv0 = (u32)f2bf(h0); if (hv0 >= 0xC000u) hv0 = 0xBF80u;  // liveness clamp
      u32 hv1 = (u32)f2bf(h1); if (hv1 >= 0xC000u) hv1 = 0xBF80u;
      if (r15 < 8) {
        u16* sp = bqslot + (size_t)it * 8192 + be * 1024 + j * 32 + 8 * w + q;
        asm volatile("global_store_short %0, %1, off sc0 sc1"
                     :: "v"(sp), "v"(hv0) : "memory");
        asm volatile("global_store_short %0, %1, off sc0 sc1"
                     :: "v"(sp + 4), "v"(hv1) : "memory");
      }
      // issue-order join only; flag is a wake-up hint (validity is in-band)
      __builtin_amdgcn_s_barrier();
      if (tid == 0)
        __hip_atomic_store(flags + bq * 32 + j, it + 1,
                           __ATOMIC_RELAXED, __HIP_MEMORY_SCOPE_AGENT);
    }
  }
}

// ---------------- launch ----------------
extern "C" void kernel_launch(void* const* d_in, const int* in_sizes, int n_in,
                              void* d_out, int out_size, void* d_ws, size_t ws_size,
                              hipStream_t stream) {
  const float* x  = (const float*)d_in[0];
  const float* Ui = (const float*)d_in[1];
  const float* Vi = (const float*)d_in[2];
  const float* bi = (const float*)d_in[3];
  const float* Uf = (const float*)d_in[4];
  const float* Vf = (const float*)d_in[5];
  const float* bf_ = (const float*)d_in[6];
  const float* Uc = (const float*)d_in[7];
  const float* Vc = (const float*)d_in[8];
  const float* bc = (const float*)d_in[9];
  const float* Uo = (const float*)d_in[10];
  const float* Vo = (const float*)d_in[11];
  const float* bo = (const float*)d_in[12];

  char* ws = (char*)d_ws;
  // flags 1KB @0 | xb/hseq 64MB @1MB (aliased; kernel-end L2 flush makes the
  // cross-kernel handoff safe, all hseq accesses are sc0 sc1) | UbT 8MB @65MB |
  // VbT 8MB @73MB | bb 16KB @81MB | xp 255.5MB @81MB+64KB  (~337MB)
  int* flags = (int*)ws;
  u16* xb    = (u16*)(ws + (size_t)(1 << 20));
  u16* hseq  = (u16*)(ws + (size_t)(1 << 20));
  u16* UbT   = (u16*)(ws + (size_t)(1 << 20) + ((size_t)64 << 20));
  u16* VbT   = (u16*)(ws + (size_t)(1 << 20) + ((size_t)72 << 20));
  float* bb  = (float*)(ws + (size_t)(1 << 20) + ((size_t)80 << 20));
  u16* xp    = (u16*)(ws + (size_t)(1 << 20) + ((size_t)80 << 20) + (1 << 16));

  conv_x<<<4096, 256, 0, stream>>>(x, xb);
  conv_u<<<1024, 256, 0, stream>>>(Ui, Uf, Uc, Uo, UbT);
  conv_u<<<1024, 256, 0, stream>>>(Vi, Vf, Vc, Vo, VbT);
  conv_b<<<16, 256, 0, stream>>>(bi, bf_, bc, bo, bb);
  gemm_xproj<<<8192, 256, 0, stream>>>(xb, UbT, bb, xp);
  init_sent<<<2048, 256, 0, stream>>>((u32*)hseq, flags);
  lstm_rec<<<256, 256, 0, stream>>>(VbT, xp, hseq, flags, (float*)d_out);
}